// Round 2
// baseline (822.852 us; speedup 1.0000x reference)
//
#include <hip/hip_runtime.h>
#include <hip/hip_bf16.h>
#include <cstdint>

typedef __bf16 bf16;
typedef bf16 bf16x8 __attribute__((ext_vector_type(8)));
typedef float floatx4 __attribute__((ext_vector_type(4)));

#define EPS_F 1e-5f

// ---------------------------------------------------------------------------
// k_convert: fp32 -> bf16, 8 elems/thread
// ---------------------------------------------------------------------------
__global__ void k_convert(const float* __restrict__ src, bf16* __restrict__ dst)
{
  long i = ((long)blockIdx.x * 256 + threadIdx.x) * 8;
  floatx4 a = *reinterpret_cast<const floatx4*>(src + i);
  floatx4 b = *reinterpret_cast<const floatx4*>(src + i + 4);
  bf16x8 o;
  #pragma unroll
  for (int e = 0; e < 4; ++e) { o[e] = (bf16)a[e]; o[4 + e] = (bf16)b[e]; }
  *reinterpret_cast<bf16x8*>(dst + i) = o;
}

// ---------------------------------------------------------------------------
// k_pre: build fused weight WcatT (1024 x 512, row j = output feature, K-contig)
//   rows 0..511   : Wfx^T
//   rows 512..1023: Wlog^T = (Wx_h @ Wslice)^T * invtemp_h
// bcat: fused bias (fp32).
// ---------------------------------------------------------------------------
__global__ void k_pre(const float* __restrict__ Wx, const float* __restrict__ bx,
                      const float* __restrict__ Wfx, const float* __restrict__ bfx,
                      const float* __restrict__ Wslice, const float* __restrict__ bslice,
                      const float* __restrict__ temp,
                      bf16* __restrict__ WcatT, float* __restrict__ bcat)
{
  __shared__ float sW[64];
  int j = blockIdx.x;
  int t = threadIdx.x;
  if (j < 512) {
    for (int c = t; c < 512; c += 256)
      WcatT[(size_t)j * 512 + c] = (bf16)Wfx[(size_t)c * 512 + j];
    if (t == 0) bcat[j] = bfx[j];
  } else {
    int jj = j - 512;
    int h = jj >> 6, g = jj & 63;
    if (t < 64) sW[t] = Wslice[t * 64 + g];
    __syncthreads();
    float tv = temp[h];
    tv = fminf(fmaxf(tv, 0.1f), 5.0f);
    float invt = 1.0f / tv;
    for (int c = t; c < 512; c += 256) {
      const float* wrow = Wx + (size_t)c * 512 + h * 64;
      float acc = 0.f;
      #pragma unroll
      for (int d = 0; d < 64; ++d) acc += wrow[d] * sW[d];
      WcatT[(size_t)j * 512 + c] = (bf16)(acc * invt);
    }
    if (t == 0) {
      float acc = 0.f;
      for (int d = 0; d < 64; ++d) acc += bx[h * 64 + d] * sW[d];
      bcat[j] = (acc + bslice[g]) * invt;
    }
  }
}

// ---------------------------------------------------------------------------
// k_gemm: C(M x Nc) = A(M x 512, lda) @ BT(Nc x 512)^T + bias, fp32 acc.
// 128x128 tile, 4 waves 2x2, each wave 64x64 via 4x4 MFMA 16x16x32 tiles.
// Fragment maps (verified gfx950): A: m=lane&15, k=quad*8+j
//                                  B: n=lane&15, k=quad*8+j (from BT rows)
//                                C/D: col=lane&15, row=quad*4+r
// ---------------------------------------------------------------------------
template <typename OutT>
__global__ __launch_bounds__(256, 2) void k_gemm(
    const bf16* __restrict__ A, const bf16* __restrict__ BT,
    OutT* __restrict__ C, const float* __restrict__ bias,
    long Abatch, long Bbatch, long Cbatch, int lda, int ldc)
{
  __shared__ bf16 As[128 * 72];
  __shared__ bf16 Bs[128 * 72];
  const int t = threadIdx.x;
  const int lane = t & 63;
  const int wave = t >> 6;
  const int wm = wave >> 1, wn = wave & 1;
  const int zb = blockIdx.z;
  const bf16* Ab = A + (long)zb * Abatch;
  const bf16* Bb = BT + (long)zb * Bbatch;
  OutT* Cb = C + (long)zb * Cbatch;
  const int N0 = blockIdx.x * 128;
  const int M0 = blockIdx.y * 128;
  const int trow = t >> 3;  // 0..31
  const int c8 = t & 7;     // 0..7
  const int lm = lane & 15;
  const int quad = lane >> 4;

  floatx4 acc[4][4] = {};

  for (int kt = 0; kt < 8; ++kt) {
    const int k0 = kt * 64;
    #pragma unroll
    for (int i = 0; i < 4; ++i) {
      int row = trow + i * 32;
      bf16x8 va = *reinterpret_cast<const bf16x8*>(Ab + (long)(M0 + row) * lda + k0 + c8 * 8);
      *reinterpret_cast<bf16x8*>(&As[row * 72 + c8 * 8]) = va;
      bf16x8 vb = *reinterpret_cast<const bf16x8*>(Bb + (long)(N0 + row) * 512 + k0 + c8 * 8);
      *reinterpret_cast<bf16x8*>(&Bs[row * 72 + c8 * 8]) = vb;
    }
    __syncthreads();
    #pragma unroll
    for (int s = 0; s < 2; ++s) {
      const int kl = s * 32 + quad * 8;
      bf16x8 af[4], bfr[4];
      #pragma unroll
      for (int i = 0; i < 4; ++i)
        af[i] = *reinterpret_cast<const bf16x8*>(&As[(wm * 64 + i * 16 + lm) * 72 + kl]);
      #pragma unroll
      for (int j = 0; j < 4; ++j)
        bfr[j] = *reinterpret_cast<const bf16x8*>(&Bs[(wn * 64 + j * 16 + lm) * 72 + kl]);
      #pragma unroll
      for (int i = 0; i < 4; ++i)
        #pragma unroll
        for (int j = 0; j < 4; ++j)
          acc[i][j] = __builtin_amdgcn_mfma_f32_16x16x32_bf16(af[i], bfr[j], acc[i][j], 0, 0, 0);
    }
    __syncthreads();
  }
  #pragma unroll
  for (int i = 0; i < 4; ++i) {
    const int gr0 = M0 + wm * 64 + i * 16 + quad * 4;
    #pragma unroll
    for (int j = 0; j < 4; ++j) {
      const int gc = N0 + wn * 64 + j * 16 + lm;
      const float bv = bias[gc];
      #pragma unroll
      for (int r = 0; r < 4; ++r)
        Cb[(long)(gr0 + r) * ldc + gc] = (OutT)(acc[i][j][r] + bv);
    }
  }
}

// ---------------------------------------------------------------------------
// k_softmax: in-place softmax over 64 logits per (row, h) in mid's cols 512..
// ---------------------------------------------------------------------------
__global__ void k_softmax(bf16* __restrict__ mid)
{
  long gid = (long)blockIdx.x * 256 + threadIdx.x;  // < 524288
  long row = gid >> 3;
  int h = (int)(gid & 7);
  bf16* p = mid + row * 1024 + 512 + h * 64;
  bf16x8 v[8];
  #pragma unroll
  for (int i = 0; i < 8; ++i) v[i] = *reinterpret_cast<const bf16x8*>(p + i * 8);
  float mx = -1e30f;
  #pragma unroll
  for (int i = 0; i < 8; ++i)
    #pragma unroll
    for (int e = 0; e < 8; ++e) mx = fmaxf(mx, (float)v[i][e]);
  float ex[64];
  float s = 0.f;
  #pragma unroll
  for (int i = 0; i < 8; ++i)
    #pragma unroll
    for (int e = 0; e < 8; ++e) {
      float E = __expf((float)v[i][e] - mx);
      ex[i * 8 + e] = E;
      s += E;
    }
  float inv = 1.0f / s;
  #pragma unroll
  for (int i = 0; i < 8; ++i) {
    bf16x8 o;
    #pragma unroll
    for (int e = 0; e < 8; ++e) o[e] = (bf16)(ex[i * 8 + e] * inv);
    *reinterpret_cast<bf16x8*>(p + i * 8) = o;
  }
}

// ---------------------------------------------------------------------------
// k_tokens: per (b,h): raw[g,c] += sum_n w[n,g]*fx[n,c]; norm[g] += sum_n w[n,g]
// fx = mid[:, h*64..], w = mid[:, 512+h*64..]. split-K over n, fp32 atomics.
// ---------------------------------------------------------------------------
__global__ __launch_bounds__(256) void k_tokens(const bf16* __restrict__ mid,
                                                float* __restrict__ raw,
                                                float* __restrict__ norm)
{
  __shared__ float wt[64][72];
  __shared__ float ft[64][72];
  int kc = blockIdx.x;  // 0..31
  int bh = blockIdx.y;  // 0..15
  int b = bh >> 3, h = bh & 7;
  long rbase = (long)b * 32768 + (long)kc * 1024;
  int t = threadIdx.x;
  int lrow = t >> 2, seg = t & 3;
  int tg = t >> 4, tc = t & 15;
  float acc[4][4] = {};
  float na[4] = {0.f, 0.f, 0.f, 0.f};
  for (int sub = 0; sub < 16; ++sub) {
    long r0 = rbase + sub * 64 + lrow;
    const bf16* fsrc = mid + r0 * 1024 + h * 64 + seg * 16;
    const bf16* wsrc = mid + r0 * 1024 + 512 + h * 64 + seg * 16;
    bf16x8 w0 = *(const bf16x8*)wsrc, w1 = *(const bf16x8*)(wsrc + 8);
    bf16x8 f0 = *(const bf16x8*)fsrc, f1 = *(const bf16x8*)(fsrc + 8);
    #pragma unroll
    for (int e = 0; e < 8; ++e) {
      wt[lrow][seg * 16 + e] = (float)w0[e];
      wt[lrow][seg * 16 + 8 + e] = (float)w1[e];
      ft[lrow][seg * 16 + e] = (float)f0[e];
      ft[lrow][seg * 16 + 8 + e] = (float)f1[e];
    }
    __syncthreads();
    #pragma unroll 4
    for (int n = 0; n < 64; ++n) {
      floatx4 wv = *(const floatx4*)&wt[n][tg * 4];
      floatx4 fv = *(const floatx4*)&ft[n][tc * 4];
      #pragma unroll
      for (int gi = 0; gi < 4; ++gi)
        #pragma unroll
        for (int ci = 0; ci < 4; ++ci) acc[gi][ci] += wv[gi] * fv[ci];
      if (tc == 0) {
        #pragma unroll
        for (int gi = 0; gi < 4; ++gi) na[gi] += wv[gi];
      }
    }
    __syncthreads();
  }
  float* rb = raw + (size_t)bh * 4096;
  #pragma unroll
  for (int gi = 0; gi < 4; ++gi)
    #pragma unroll
    for (int ci = 0; ci < 4; ++ci)
      atomicAdd(&rb[(tg * 4 + gi) * 64 + tc * 4 + ci], acc[gi][ci]);
  if (tc == 0) {
    #pragma unroll
    for (int gi = 0; gi < 4; ++gi) atomicAdd(&norm[bh * 64 + tg * 4 + gi], na[gi]);
  }
}

// ---------------------------------------------------------------------------
// k_ctx: ck/cv = context(b,h) (64x256) @ Wck/Wcv (256x64) + bias -> fp32 ws
// ---------------------------------------------------------------------------
__global__ __launch_bounds__(256) void k_ctx(const float* __restrict__ ctx,
                                             const float* __restrict__ Wck, const float* __restrict__ bck,
                                             const float* __restrict__ Wcv, const float* __restrict__ bcv,
                                             float* __restrict__ ckbuf, float* __restrict__ cvbuf)
{
  __shared__ float sW[256 * 64];  // 64 KB
  int bh = blockIdx.x;
  int which = blockIdx.y;
  const float* W = which ? Wcv : Wck;
  const float* bb = which ? bcv : bck;
  float* outp = which ? cvbuf : ckbuf;
  int t = threadIdx.x;
  for (int i = t; i < 4096; i += 256)
    *(floatx4*)&sW[i * 4] = *(const floatx4*)(W + i * 4);
  __syncthreads();
  int r = t >> 2, c0 = (t & 3) * 16;
  const float* crow = ctx + ((size_t)bh * 64 + r) * 256;
  float acc[16] = {};
  for (int e4 = 0; e4 < 64; ++e4) {
    floatx4 cvv = *(const floatx4*)(crow + e4 * 4);
    #pragma unroll
    for (int ee = 0; ee < 4; ++ee) {
      float cval = cvv[ee];
      int e = e4 * 4 + ee;
      #pragma unroll
      for (int q = 0; q < 4; ++q) {
        floatx4 w4 = *(const floatx4*)&sW[e * 64 + c0 + q * 4];
        acc[q * 4 + 0] += cval * w4[0];
        acc[q * 4 + 1] += cval * w4[1];
        acc[q * 4 + 2] += cval * w4[2];
        acc[q * 4 + 3] += cval * w4[3];
      }
    }
  }
  size_t base = (size_t)bh * 4096 + r * 64 + c0;
  #pragma unroll
  for (int i = 0; i < 16; ++i) outp[base + i] = acc[i] + bb[c0 + i];
}

// ---------------------------------------------------------------------------
// k_attn: per (b,h): tokens = raw/(norm+eps); q/k/v/cq proj; self-attn;
// cross-attn vs precomputed ck/cv; gated mix -> ot (fp32).
// ---------------------------------------------------------------------------
__global__ __launch_bounds__(256) void k_attn(
    const float* __restrict__ raw, const float* __restrict__ norm,
    const float* __restrict__ Wq, const float* __restrict__ bq,
    const float* __restrict__ Wk, const float* __restrict__ bk,
    const float* __restrict__ Wv, const float* __restrict__ bv,
    const float* __restrict__ Wcq, const float* __restrict__ bcq,
    const float* __restrict__ ck, const float* __restrict__ cv,
    const float* __restrict__ smix, float* __restrict__ ot)
{
  __shared__ float T0[4096];  // tok -> P -> P2
  __shared__ float T1[4096];  // q   -> ck
  __shared__ float T2[4096];  // k   -> cv
  __shared__ float T3[4096];  // v   -> cq
  int bh = blockIdx.x;
  int t = threadIdx.x;
  int r = t >> 2;
  int c0 = (t & 3) * 16;
  size_t base = (size_t)bh * 4096;

  // P1: tokens
  float invn = 1.0f / (norm[bh * 64 + r] + EPS_F);
  #pragma unroll
  for (int i = 0; i < 16; ++i)
    T0[r * 64 + c0 + i] = raw[base + r * 64 + c0 + i] * invn;
  __syncthreads();

  // P2: q,k,v (LDS), cq (regs)
  float acq[16] = {};
  {
    float aq[16] = {}, ak[16] = {}, av[16] = {};
    for (int d = 0; d < 64; ++d) {
      float x = T0[r * 64 + d];
      #pragma unroll
      for (int q = 0; q < 4; ++q) {
        floatx4 wq = *(const floatx4*)(Wq + d * 64 + c0 + q * 4);
        floatx4 wk = *(const floatx4*)(Wk + d * 64 + c0 + q * 4);
        floatx4 wv = *(const floatx4*)(Wv + d * 64 + c0 + q * 4);
        floatx4 wc = *(const floatx4*)(Wcq + d * 64 + c0 + q * 4);
        #pragma unroll
        for (int e = 0; e < 4; ++e) {
          aq[q * 4 + e] += x * wq[e];
          ak[q * 4 + e] += x * wk[e];
          av[q * 4 + e] += x * wv[e];
          acq[q * 4 + e] += x * wc[e];
        }
      }
    }
    __syncthreads();  // all reads of T0 done
    #pragma unroll
    for (int i = 0; i < 16; ++i) {
      T1[r * 64 + c0 + i] = aq[i] + bq[c0 + i];
      T2[r * 64 + c0 + i] = ak[i] + bk[c0 + i];
      T3[r * 64 + c0 + i] = av[i] + bv[c0 + i];
      acq[i] += bcq[c0 + i];
    }
  }
  __syncthreads();

  // P3: self-attn scores + softmax -> P in T0
  {
    float p[16];
    float mx = -1e30f;
    #pragma unroll
    for (int i = 0; i < 16; ++i) {
      int cc = c0 + i;
      float s = 0.f;
      #pragma unroll
      for (int d4 = 0; d4 < 16; ++d4) {
        floatx4 qv = *(const floatx4*)&T1[r * 64 + d4 * 4];
        floatx4 kv = *(const floatx4*)&T2[cc * 64 + d4 * 4];
        s += qv[0] * kv[0] + qv[1] * kv[1] + qv[2] * kv[2] + qv[3] * kv[3];
      }
      p[i] = s * 0.125f;
      mx = fmaxf(mx, p[i]);
    }
    mx = fmaxf(mx, __shfl_xor(mx, 1));
    mx = fmaxf(mx, __shfl_xor(mx, 2));
    float sum = 0.f;
    #pragma unroll
    for (int i = 0; i < 16; ++i) { p[i] = __expf(p[i] - mx); sum += p[i]; }
    sum += __shfl_xor(sum, 1);
    sum += __shfl_xor(sum, 2);
    float inv = 1.0f / sum;
    #pragma unroll
    for (int i = 0; i < 16; ++i) T0[r * 64 + c0 + i] = p[i] * inv;
  }
  __syncthreads();

  // P4: sa = P @ v
  float sa[16] = {};
  for (int g = 0; g < 64; ++g) {
    float pv = T0[r * 64 + g];
    #pragma unroll
    for (int i4 = 0; i4 < 4; ++i4) {
      floatx4 vv = *(const floatx4*)&T3[g * 64 + c0 + i4 * 4];
      sa[i4 * 4 + 0] += pv * vv[0];
      sa[i4 * 4 + 1] += pv * vv[1];
      sa[i4 * 4 + 2] += pv * vv[2];
      sa[i4 * 4 + 3] += pv * vv[3];
    }
  }
  __syncthreads();

  // P5: cq -> T3, ck -> T1, cv -> T2
  #pragma unroll
  for (int i = 0; i < 16; ++i) {
    T3[r * 64 + c0 + i] = acq[i];
    T1[r * 64 + c0 + i] = ck[base + r * 64 + c0 + i];
    T2[r * 64 + c0 + i] = cv[base + r * 64 + c0 + i];
  }
  __syncthreads();

  // P6: cross-attn scores + softmax -> P2 in T0
  {
    float p[16];
    float mx = -1e30f;
    #pragma unroll
    for (int i = 0; i < 16; ++i) {
      int cc = c0 + i;
      float s = 0.f;
      #pragma unroll
      for (int d4 = 0; d4 < 16; ++d4) {
        floatx4 qv = *(const floatx4*)&T3[r * 64 + d4 * 4];
        floatx4 kv = *(const floatx4*)&T1[cc * 64 + d4 * 4];
        s += qv[0] * kv[0] + qv[1] * kv[1] + qv[2] * kv[2] + qv[3] * kv[3];
      }
      p[i] = s * 0.125f;
      mx = fmaxf(mx, p[i]);
    }
    mx = fmaxf(mx, __shfl_xor(mx, 1));
    mx = fmaxf(mx, __shfl_xor(mx, 2));
    float sum = 0.f;
    #pragma unroll
    for (int i = 0; i < 16; ++i) { p[i] = __expf(p[i] - mx); sum += p[i]; }
    sum += __shfl_xor(sum, 1);
    sum += __shfl_xor(sum, 2);
    float inv = 1.0f / sum;
    #pragma unroll
    for (int i = 0; i < 16; ++i) T0[r * 64 + c0 + i] = p[i] * inv;
  }
  __syncthreads();

  // P7: ca = P2 @ cv; mix; write ot
  float ca[16] = {};
  for (int g = 0; g < 64; ++g) {
    float pv = T0[r * 64 + g];
    #pragma unroll
    for (int i4 = 0; i4 < 4; ++i4) {
      floatx4 vv = *(const floatx4*)&T2[g * 64 + c0 + i4 * 4];
      ca[i4 * 4 + 0] += pv * vv[0];
      ca[i4 * 4 + 1] += pv * vv[1];
      ca[i4 * 4 + 2] += pv * vv[2];
      ca[i4 * 4 + 3] += pv * vv[3];
    }
  }
  float gmix = 1.0f / (1.0f + __expf(-smix[0]));
  #pragma unroll
  for (int i = 0; i < 16; ++i)
    ot[base + r * 64 + c0 + i] = gmix * sa[i] + (1.0f - gmix) * ca[i];
}

// ---------------------------------------------------------------------------
// k_mcat: McatT[b][j][h*64+g] = sum_c ot[b,h,g,c] * Wo[h*64+c][j]  (bf16 out)
// ---------------------------------------------------------------------------
__global__ __launch_bounds__(256) void k_mcat(const float* __restrict__ ot,
                                              const float* __restrict__ Wo,
                                              bf16* __restrict__ McatT)
{
  __shared__ float woS[64][68];
  __shared__ float otS[64][68];
  int jt = blockIdx.x;  // 0..7
  int b = blockIdx.y;   // 0..1
  int t = threadIdx.x;
  int jl = t >> 2;  // 0..63
  int s4 = t & 3;   // 0..3
  int srow = t >> 2, sc = t & 3;
  for (int h = 0; h < 8; ++h) {
    {
      const float* src = Wo + (size_t)(h * 64 + srow) * 512 + jt * 64 + sc * 16;
      #pragma unroll
      for (int q = 0; q < 4; ++q)
        *reinterpret_cast<floatx4*>(&woS[srow][sc * 16 + q * 4]) =
            *reinterpret_cast<const floatx4*>(src + q * 4);
    }
    {
      const float* src = ot + ((size_t)(b * 8 + h)) * 4096 + srow * 64 + sc * 16;
      #pragma unroll
      for (int q = 0; q < 4; ++q)
        *reinterpret_cast<floatx4*>(&otS[srow][sc * 16 + q * 4]) =
            *reinterpret_cast<const floatx4*>(src + q * 4);
    }
    __syncthreads();
    float wcol[64];
    #pragma unroll
    for (int c = 0; c < 64; ++c) wcol[c] = woS[c][jl];
    #pragma unroll
    for (int g = 0; g < 16; ++g) {
      int gg = s4 * 16 + g;
      float a = 0.f;
      #pragma unroll
      for (int c = 0; c < 64; ++c) a += otS[gg][c] * wcol[c];
      McatT[((size_t)b * 512 + (size_t)jt * 64 + jl) * 512 + h * 64 + gg] = (bf16)a;
    }
    __syncthreads();
  }
}

// ---------------------------------------------------------------------------
extern "C" void kernel_launch(void* const* d_in, const int* in_sizes, int n_in,
                              void* d_out, int out_size, void* d_ws, size_t ws_size,
                              hipStream_t stream)
{
  const float* x      = (const float*)d_in[0];
  const float* contxt = (const float*)d_in[1];
  const float* Wx     = (const float*)d_in[2];
  const float* bx     = (const float*)d_in[3];
  const float* Wfx    = (const float*)d_in[4];
  const float* bfx    = (const float*)d_in[5];
  const float* Wslice = (const float*)d_in[6];
  const float* bslice = (const float*)d_in[7];
  const float* temp   = (const float*)d_in[8];
  const float* Wq  = (const float*)d_in[9];  const float* bq  = (const float*)d_in[10];
  const float* Wk  = (const float*)d_in[11]; const float* bk  = (const float*)d_in[12];
  const float* Wv  = (const float*)d_in[13]; const float* bv  = (const float*)d_in[14];
  const float* Wcq = (const float*)d_in[15]; const float* bcq = (const float*)d_in[16];
  const float* Wck = (const float*)d_in[17]; const float* bck = (const float*)d_in[18];
  const float* Wcv = (const float*)d_in[19]; const float* bcv = (const float*)d_in[20];
  const float* smix = (const float*)d_in[21];
  const float* Wo = (const float*)d_in[22];  const float* bo = (const float*)d_in[23];
  float* out = (float*)d_out;

  char* ws = (char*)d_ws;
  // ws layout (bytes, all 256-aligned):
  bf16*  midbuf = (bf16*)(ws + 0);             // 65536 x 1024 bf16 (fx | logits->w) : 134217728
  bf16*  xb     = (bf16*)(ws + 134217728);     // 65536 x 512 bf16                   : 67108864
  bf16*  WcatT  = (bf16*)(ws + 201326592);     // 1024 x 512 bf16                    : 1048576
  bf16*  McatT  = (bf16*)(ws + 202375168);     // 2 x 512 x 512 bf16                 : 1048576
  float* bcat   = (float*)(ws + 203423744);    // 1024 f32                           : 4096
  float* traw   = (float*)(ws + 203427840);    // 16*4096 f32                        : 262144
  float* norm   = (float*)(ws + 203689984);    // 16*64 f32 (adjacent to traw)       : 4096
  float* otbuf  = (float*)(ws + 203694080);    // 16*4096 f32                        : 262144
  float* ckbuf  = (float*)(ws + 203956224);    // 16*4096 f32                        : 262144
  float* cvbuf  = (float*)(ws + 204218368);    // 16*4096 f32                        : 262144
  // total ~204.5 MB

  // zero split-K accumulators (traw + norm are adjacent)
  hipMemsetAsync(traw, 0, (16 * 4096 + 16 * 64) * sizeof(float), stream);

  // x (fp32) -> xb (bf16)
  k_convert<<<dim3(16384), 256, 0, stream>>>(x, xb);

  k_pre<<<dim3(1024), 256, 0, stream>>>(Wx, bx, Wfx, bfx, Wslice, bslice, temp,
                                        WcatT, bcat);

  // GEMM 1: xb (65536x512) @ WcatT^T -> midbuf (65536x1024)  [fx | logits]
  k_gemm<bf16><<<dim3(8, 512, 1), 256, 0, stream>>>(
      xb, WcatT, midbuf, bcat, 0, 0, 0, 512, 1024);

  // in-place softmax on logits half -> w
  k_softmax<<<dim3(2048), 256, 0, stream>>>(midbuf);

  k_tokens<<<dim3(32, 16), 256, 0, stream>>>(midbuf, traw, norm);

  k_ctx<<<dim3(16, 2), 256, 0, stream>>>(contxt, Wck, bck, Wcv, bcv, ckbuf, cvbuf);

  k_attn<<<dim3(16), 256, 0, stream>>>(traw, norm, Wq, bq, Wk, bk, Wv, bv, Wcq, bcq,
                                       ckbuf, cvbuf, smix, otbuf);

  k_mcat<<<dim3(8, 2), 256, 0, stream>>>(otbuf, Wo, McatT);

  // GEMM 2: w[b] (32768x512, lda=1024 in midbuf) @ McatT[b]^T + bo -> out[b] (fp32)
  k_gemm<float><<<dim3(4, 256, 2), 256, 0, stream>>>(
      midbuf + 512, McatT, out, bo,
      (long)32768 * 1024, (long)512 * 512, (long)32768 * 512, 1024, 512);
}

// Round 3
// 750.686 us; speedup vs baseline: 1.0961x; 1.0961x over previous
//
#include <hip/hip_runtime.h>
#include <hip/hip_bf16.h>
#include <cstdint>

typedef __bf16 bf16;
typedef bf16 bf16x8 __attribute__((ext_vector_type(8)));
typedef float floatx4 __attribute__((ext_vector_type(4)));

#define EPS_F 1e-5f

__device__ __forceinline__ void async16(const bf16* g, bf16* l)
{
  __builtin_amdgcn_global_load_lds(
      (const __attribute__((address_space(1))) void*)g,
      (__attribute__((address_space(3))) void*)l, 16, 0, 0);
}

// ---------------------------------------------------------------------------
// k_prep: fused  [0,16384): x fp32->bf16   [16384,17408): build WcatT/bcat
//                [17408,17473): zero traw+norm (65 * 1024 floats)
// ---------------------------------------------------------------------------
__global__ void k_prep(const float* __restrict__ x, bf16* __restrict__ xb,
                       const float* __restrict__ Wx, const float* __restrict__ bx,
                       const float* __restrict__ Wfx, const float* __restrict__ bfx,
                       const float* __restrict__ Wslice, const float* __restrict__ bslice,
                       const float* __restrict__ temp,
                       bf16* __restrict__ WcatT, float* __restrict__ bcat,
                       float* __restrict__ zbase)
{
  __shared__ float sW[64];
  int bb = blockIdx.x;
  int t = threadIdx.x;
  if (bb < 16384) {
    long i = ((long)bb * 256 + t) * 8;
    floatx4 a = *reinterpret_cast<const floatx4*>(x + i);
    floatx4 b = *reinterpret_cast<const floatx4*>(x + i + 4);
    bf16x8 o;
    #pragma unroll
    for (int e = 0; e < 4; ++e) { o[e] = (bf16)a[e]; o[4 + e] = (bf16)b[e]; }
    *reinterpret_cast<bf16x8*>(xb + i) = o;
  } else if (bb < 17408) {
    int j = bb - 16384;
    if (j < 512) {
      for (int c = t; c < 512; c += 256)
        WcatT[(size_t)j * 512 + c] = (bf16)Wfx[(size_t)c * 512 + j];
      if (t == 0) bcat[j] = bfx[j];
    } else {
      int jj = j - 512;
      int h = jj >> 6, g = jj & 63;
      if (t < 64) sW[t] = Wslice[t * 64 + g];
      __syncthreads();
      float tv = temp[h];
      tv = fminf(fmaxf(tv, 0.1f), 5.0f);
      float invt = 1.0f / tv;
      for (int c = t; c < 512; c += 256) {
        const float* wrow = Wx + (size_t)c * 512 + h * 64;
        float acc = 0.f;
        #pragma unroll
        for (int d = 0; d < 64; ++d) acc += wrow[d] * sW[d];
        WcatT[(size_t)j * 512 + c] = (bf16)(acc * invt);
      }
      if (t == 0) {
        float acc = 0.f;
        for (int d = 0; d < 64; ++d) acc += bx[h * 64 + d] * sW[d];
        bcat[j] = (acc + bslice[g]) * invt;
      }
    }
  } else {
    int z = bb - 17408;
    floatx4 zf = {0.f, 0.f, 0.f, 0.f};
    *reinterpret_cast<floatx4*>(&zbase[((long)z * 256 + t) * 4]) = zf;
  }
}

// ---------------------------------------------------------------------------
// k_gemm: C(M x Nc) = A(M x 512, lda) @ BT(Nc x 512)^T + bias, fp32 acc.
// 128x128 tile, 4 waves 2x2. global_load_lds 16B staging, unpadded LDS.
// XCD swizzle: blocks sharing an A-band get ids {c, c+8, ..} -> same XCD.
// SM: for N0>=512 blocks apply per-head softmax in epilogue (wave = 1 head,
//     row's 64 values live in one 16-lane quad group -> shfl_xor reduce).
// ---------------------------------------------------------------------------
template <typename OutT, bool SM>
__global__ __launch_bounds__(256, 2) void k_gemm(
    const bf16* __restrict__ A, const bf16* __restrict__ BT,
    OutT* __restrict__ C, const float* __restrict__ bias,
    long Abatch, long Bbatch, long Cbatch, int lda, int ldc, int grid_n)
{
  __shared__ bf16 As[128 * 64];
  __shared__ bf16 Bs[128 * 64];
  const int t = threadIdx.x;
  const int lane = t & 63;
  const int wave = t >> 6;
  const int wm = wave >> 1, wn = wave & 1;
  const int zb = blockIdx.z;
  const bf16* Ab = A + (long)zb * Abatch;
  const bf16* Bb = BT + (long)zb * Bbatch;
  OutT* Cb = C + (long)zb * Cbatch;

  // swizzled decode
  const int L = blockIdx.x;
  const int cx = L & 7;
  const int nb = (L >> 3) % grid_n;
  const int chunk = L / (8 * grid_n);
  const int M0 = (chunk * 8 + cx) * 128;
  const int N0 = nb * 128;

  const int lm = lane & 15;
  const int quad = lane >> 4;
  const int srow = lane >> 3;   // 0..7 within chunk
  const int sc8 = lane & 7;     // 16B col within row

  floatx4 acc[4][4] = {};

  for (int kt = 0; kt < 8; ++kt) {
    const int k0 = kt * 64;
    const bf16* gA = Ab + (long)(M0 + wave * 32 + srow) * lda + k0 + sc8 * 8;
    const bf16* gB = Bb + (long)(N0 + wave * 32 + srow) * 512 + k0 + sc8 * 8;
    bf16* lA = &As[wave * 2048];
    bf16* lB = &Bs[wave * 2048];
    #pragma unroll
    for (int i = 0; i < 4; ++i) {
      async16(gA + (long)i * 8 * lda, lA + i * 512);
      async16(gB + (long)i * 8 * 512, lB + i * 512);
    }
    __syncthreads();
    #pragma unroll
    for (int s = 0; s < 2; ++s) {
      const int kl = s * 32 + quad * 8;
      bf16x8 af[4], bfr[4];
      #pragma unroll
      for (int i = 0; i < 4; ++i)
        af[i] = *reinterpret_cast<const bf16x8*>(&As[(wm * 64 + i * 16 + lm) * 64 + kl]);
      #pragma unroll
      for (int j = 0; j < 4; ++j)
        bfr[j] = *reinterpret_cast<const bf16x8*>(&Bs[(wn * 64 + j * 16 + lm) * 64 + kl]);
      #pragma unroll
      for (int i = 0; i < 4; ++i)
        #pragma unroll
        for (int j = 0; j < 4; ++j)
          acc[i][j] = __builtin_amdgcn_mfma_f32_16x16x32_bf16(af[i], bfr[j], acc[i][j], 0, 0, 0);
    }
    __syncthreads();
  }

  float bv[4];
  #pragma unroll
  for (int j = 0; j < 4; ++j) bv[j] = bias[N0 + wn * 64 + j * 16 + lm];

  if (SM && N0 >= 512) {
    // softmax over this wave's 64 cols (one head) per row
    #pragma unroll
    for (int i = 0; i < 4; ++i) {
      #pragma unroll
      for (int r = 0; r < 4; ++r) {
        float v[4];
        #pragma unroll
        for (int j = 0; j < 4; ++j) v[j] = acc[i][j][r] + bv[j];
        float m = fmaxf(fmaxf(v[0], v[1]), fmaxf(v[2], v[3]));
        m = fmaxf(m, __shfl_xor(m, 1));
        m = fmaxf(m, __shfl_xor(m, 2));
        m = fmaxf(m, __shfl_xor(m, 4));
        m = fmaxf(m, __shfl_xor(m, 8));
        float e[4], s = 0.f;
        #pragma unroll
        for (int j = 0; j < 4; ++j) { e[j] = __expf(v[j] - m); s += e[j]; }
        s += __shfl_xor(s, 1);
        s += __shfl_xor(s, 2);
        s += __shfl_xor(s, 4);
        s += __shfl_xor(s, 8);
        float inv = 1.0f / s;
        const long gr = M0 + wm * 64 + i * 16 + quad * 4 + r;
        #pragma unroll
        for (int j = 0; j < 4; ++j)
          Cb[gr * ldc + N0 + wn * 64 + j * 16 + lm] = (OutT)(e[j] * inv);
      }
    }
  } else {
    #pragma unroll
    for (int i = 0; i < 4; ++i) {
      const int gr0 = M0 + wm * 64 + i * 16 + quad * 4;
      #pragma unroll
      for (int j = 0; j < 4; ++j) {
        const int gc = N0 + wn * 64 + j * 16 + lm;
        #pragma unroll
        for (int r = 0; r < 4; ++r)
          Cb[(long)(gr0 + r) * ldc + gc] = (OutT)(acc[i][j][r] + bv[j]);
      }
    }
  }
}

// ---------------------------------------------------------------------------
// k_tokens: per (b,h): raw[g,c] += sum_n w[n,g]*fx[n,c]; norm[g] += sum_n w[n,g]
// fx = mid[:, h*64..], w = mid[:, 512+h*64..]. split-K over n, fp32 atomics.
// ---------------------------------------------------------------------------
__global__ __launch_bounds__(256) void k_tokens(const bf16* __restrict__ mid,
                                                float* __restrict__ raw,
                                                float* __restrict__ norm)
{
  __shared__ float wt[64][72];
  __shared__ float ft[64][72];
  int kc = blockIdx.x;  // 0..31
  int bh = blockIdx.y;  // 0..15
  int b = bh >> 3, h = bh & 7;
  long rbase = (long)b * 32768 + (long)kc * 1024;
  int t = threadIdx.x;
  int lrow = t >> 2, seg = t & 3;
  int tg = t >> 4, tc = t & 15;
  float acc[4][4] = {};
  float na[4] = {0.f, 0.f, 0.f, 0.f};
  for (int sub = 0; sub < 16; ++sub) {
    long r0 = rbase + sub * 64 + lrow;
    const bf16* fsrc = mid + r0 * 1024 + h * 64 + seg * 16;
    const bf16* wsrc = mid + r0 * 1024 + 512 + h * 64 + seg * 16;
    bf16x8 w0 = *(const bf16x8*)wsrc, w1 = *(const bf16x8*)(wsrc + 8);
    bf16x8 f0 = *(const bf16x8*)fsrc, f1 = *(const bf16x8*)(fsrc + 8);
    #pragma unroll
    for (int e = 0; e < 8; ++e) {
      wt[lrow][seg * 16 + e] = (float)w0[e];
      wt[lrow][seg * 16 + 8 + e] = (float)w1[e];
      ft[lrow][seg * 16 + e] = (float)f0[e];
      ft[lrow][seg * 16 + 8 + e] = (float)f1[e];
    }
    __syncthreads();
    #pragma unroll 4
    for (int n = 0; n < 64; ++n) {
      floatx4 wv = *(const floatx4*)&wt[n][tg * 4];
      floatx4 fv = *(const floatx4*)&ft[n][tc * 4];
      #pragma unroll
      for (int gi = 0; gi < 4; ++gi)
        #pragma unroll
        for (int ci = 0; ci < 4; ++ci) acc[gi][ci] += wv[gi] * fv[ci];
      if (tc == 0) {
        #pragma unroll
        for (int gi = 0; gi < 4; ++gi) na[gi] += wv[gi];
      }
    }
    __syncthreads();
  }
  float* rb = raw + (size_t)bh * 4096;
  #pragma unroll
  for (int gi = 0; gi < 4; ++gi)
    #pragma unroll
    for (int ci = 0; ci < 4; ++ci)
      atomicAdd(&rb[(tg * 4 + gi) * 64 + tc * 4 + ci], acc[gi][ci]);
  if (tc == 0) {
    #pragma unroll
    for (int gi = 0; gi < 4; ++gi) atomicAdd(&norm[bh * 64 + tg * 4 + gi], na[gi]);
  }
}

// ---------------------------------------------------------------------------
// k_ctx: ck/cv = context(b,h) (64x256) @ Wck/Wcv (256x64) + bias -> fp32 ws
// ---------------------------------------------------------------------------
__global__ __launch_bounds__(256) void k_ctx(const float* __restrict__ ctx,
                                             const float* __restrict__ Wck, const float* __restrict__ bck,
                                             const float* __restrict__ Wcv, const float* __restrict__ bcv,
                                             float* __restrict__ ckbuf, float* __restrict__ cvbuf)
{
  __shared__ float sW[256 * 64];  // 64 KB
  int bh = blockIdx.x;
  int which = blockIdx.y;
  const float* W = which ? Wcv : Wck;
  const float* bb = which ? bcv : bck;
  float* outp = which ? cvbuf : ckbuf;
  int t = threadIdx.x;
  for (int i = t; i < 4096; i += 256)
    *(floatx4*)&sW[i * 4] = *(const floatx4*)(W + i * 4);
  __syncthreads();
  int r = t >> 2, c0 = (t & 3) * 16;
  const float* crow = ctx + ((size_t)bh * 64 + r) * 256;
  float acc[16] = {};
  for (int e4 = 0; e4 < 64; ++e4) {
    floatx4 cvv = *(const floatx4*)(crow + e4 * 4);
    #pragma unroll
    for (int ee = 0; ee < 4; ++ee) {
      float cval = cvv[ee];
      int e = e4 * 4 + ee;
      #pragma unroll
      for (int q = 0; q < 4; ++q) {
        floatx4 w4 = *(const floatx4*)&sW[e * 64 + c0 + q * 4];
        acc[q * 4 + 0] += cval * w4[0];
        acc[q * 4 + 1] += cval * w4[1];
        acc[q * 4 + 2] += cval * w4[2];
        acc[q * 4 + 3] += cval * w4[3];
      }
    }
  }
  size_t base = (size_t)bh * 4096 + r * 64 + c0;
  #pragma unroll
  for (int i = 0; i < 16; ++i) outp[base + i] = acc[i] + bb[c0 + i];
}

// ---------------------------------------------------------------------------
// k_attn: per (b,h): tokens = raw/(norm+eps); q/k/v/cq proj; self-attn;
// cross-attn vs precomputed ck/cv; gated mix -> ot (fp32).
// ---------------------------------------------------------------------------
__global__ __launch_bounds__(256) void k_attn(
    const float* __restrict__ raw, const float* __restrict__ norm,
    const float* __restrict__ Wq, const float* __restrict__ bq,
    const float* __restrict__ Wk, const float* __restrict__ bk,
    const float* __restrict__ Wv, const float* __restrict__ bv,
    const float* __restrict__ Wcq, const float* __restrict__ bcq,
    const float* __restrict__ ck, const float* __restrict__ cv,
    const float* __restrict__ smix, float* __restrict__ ot)
{
  __shared__ float T0[4096];
  __shared__ float T1[4096];
  __shared__ float T2[4096];
  __shared__ float T3[4096];
  int bh = blockIdx.x;
  int t = threadIdx.x;
  int r = t >> 2;
  int c0 = (t & 3) * 16;
  size_t base = (size_t)bh * 4096;

  float invn = 1.0f / (norm[bh * 64 + r] + EPS_F);
  #pragma unroll
  for (int i = 0; i < 16; ++i)
    T0[r * 64 + c0 + i] = raw[base + r * 64 + c0 + i] * invn;
  __syncthreads();

  float acq[16] = {};
  {
    float aq[16] = {}, ak[16] = {}, av[16] = {};
    for (int d = 0; d < 64; ++d) {
      float x = T0[r * 64 + d];
      #pragma unroll
      for (int q = 0; q < 4; ++q) {
        floatx4 wq = *(const floatx4*)(Wq + d * 64 + c0 + q * 4);
        floatx4 wk = *(const floatx4*)(Wk + d * 64 + c0 + q * 4);
        floatx4 wv = *(const floatx4*)(Wv + d * 64 + c0 + q * 4);
        floatx4 wc = *(const floatx4*)(Wcq + d * 64 + c0 + q * 4);
        #pragma unroll
        for (int e = 0; e < 4; ++e) {
          aq[q * 4 + e] += x * wq[e];
          ak[q * 4 + e] += x * wk[e];
          av[q * 4 + e] += x * wv[e];
          acq[q * 4 + e] += x * wc[e];
        }
      }
    }
    __syncthreads();
    #pragma unroll
    for (int i = 0; i < 16; ++i) {
      T1[r * 64 + c0 + i] = aq[i] + bq[c0 + i];
      T2[r * 64 + c0 + i] = ak[i] + bk[c0 + i];
      T3[r * 64 + c0 + i] = av[i] + bv[c0 + i];
      acq[i] += bcq[c0 + i];
    }
  }
  __syncthreads();

  {
    float p[16];
    float mx = -1e30f;
    #pragma unroll
    for (int i = 0; i < 16; ++i) {
      int cc = c0 + i;
      float s = 0.f;
      #pragma unroll
      for (int d4 = 0; d4 < 16; ++d4) {
        floatx4 qv = *(const floatx4*)&T1[r * 64 + d4 * 4];
        floatx4 kv = *(const floatx4*)&T2[cc * 64 + d4 * 4];
        s += qv[0] * kv[0] + qv[1] * kv[1] + qv[2] * kv[2] + qv[3] * kv[3];
      }
      p[i] = s * 0.125f;
      mx = fmaxf(mx, p[i]);
    }
    mx = fmaxf(mx, __shfl_xor(mx, 1));
    mx = fmaxf(mx, __shfl_xor(mx, 2));
    float sum = 0.f;
    #pragma unroll
    for (int i = 0; i < 16; ++i) { p[i] = __expf(p[i] - mx); sum += p[i]; }
    sum += __shfl_xor(sum, 1);
    sum += __shfl_xor(sum, 2);
    float inv = 1.0f / sum;
    #pragma unroll
    for (int i = 0; i < 16; ++i) T0[r * 64 + c0 + i] = p[i] * inv;
  }
  __syncthreads();

  float sa[16] = {};
  for (int g = 0; g < 64; ++g) {
    float pv = T0[r * 64 + g];
    #pragma unroll
    for (int i4 = 0; i4 < 4; ++i4) {
      floatx4 vv = *(const floatx4*)&T3[g * 64 + c0 + i4 * 4];
      sa[i4 * 4 + 0] += pv * vv[0];
      sa[i4 * 4 + 1] += pv * vv[1];
      sa[i4 * 4 + 2] += pv * vv[2];
      sa[i4 * 4 + 3] += pv * vv[3];
    }
  }
  __syncthreads();

  #pragma unroll
  for (int i = 0; i < 16; ++i) {
    T3[r * 64 + c0 + i] = acq[i];
    T1[r * 64 + c0 + i] = ck[base + r * 64 + c0 + i];
    T2[r * 64 + c0 + i] = cv[base + r * 64 + c0 + i];
  }
  __syncthreads();

  {
    float p[16];
    float mx = -1e30f;
    #pragma unroll
    for (int i = 0; i < 16; ++i) {
      int cc = c0 + i;
      float s = 0.f;
      #pragma unroll
      for (int d4 = 0; d4 < 16; ++d4) {
        floatx4 qv = *(const floatx4*)&T3[r * 64 + d4 * 4];
        floatx4 kv = *(const floatx4*)&T1[cc * 64 + d4 * 4];
        s += qv[0] * kv[0] + qv[1] * kv[1] + qv[2] * kv[2] + qv[3] * kv[3];
      }
      p[i] = s * 0.125f;
      mx = fmaxf(mx, p[i]);
    }
    mx = fmaxf(mx, __shfl_xor(mx, 1));
    mx = fmaxf(mx, __shfl_xor(mx, 2));
    float sum = 0.f;
    #pragma unroll
    for (int i = 0; i < 16; ++i) { p[i] = __expf(p[i] - mx); sum += p[i]; }
    sum += __shfl_xor(sum, 1);
    sum += __shfl_xor(sum, 2);
    float inv = 1.0f / sum;
    #pragma unroll
    for (int i = 0; i < 16; ++i) T0[r * 64 + c0 + i] = p[i] * inv;
  }
  __syncthreads();

  float ca[16] = {};
  for (int g = 0; g < 64; ++g) {
    float pv = T0[r * 64 + g];
    #pragma unroll
    for (int i4 = 0; i4 < 4; ++i4) {
      floatx4 vv = *(const floatx4*)&T2[g * 64 + c0 + i4 * 4];
      ca[i4 * 4 + 0] += pv * vv[0];
      ca[i4 * 4 + 1] += pv * vv[1];
      ca[i4 * 4 + 2] += pv * vv[2];
      ca[i4 * 4 + 3] += pv * vv[3];
    }
  }
  float gmix = 1.0f / (1.0f + __expf(-smix[0]));
  #pragma unroll
  for (int i = 0; i < 16; ++i)
    ot[base + r * 64 + c0 + i] = gmix * sa[i] + (1.0f - gmix) * ca[i];
}

// ---------------------------------------------------------------------------
// k_mcat: McatT[b][j][h*64+g] = sum_c ot[b,h,g,c] * Wo[h*64+c][j]  (bf16 out)
// ---------------------------------------------------------------------------
__global__ __launch_bounds__(256) void k_mcat(const float* __restrict__ ot,
                                              const float* __restrict__ Wo,
                                              bf16* __restrict__ McatT)
{
  __shared__ float woS[64][68];
  __shared__ float otS[64][68];
  int jt = blockIdx.x;  // 0..7
  int b = blockIdx.y;   // 0..1
  int t = threadIdx.x;
  int jl = t >> 2;
  int s4 = t & 3;
  int srow = t >> 2, sc = t & 3;
  for (int h = 0; h < 8; ++h) {
    {
      const float* src = Wo + (size_t)(h * 64 + srow) * 512 + jt * 64 + sc * 16;
      #pragma unroll
      for (int q = 0; q < 4; ++q)
        *reinterpret_cast<floatx4*>(&woS[srow][sc * 16 + q * 4]) =
            *reinterpret_cast<const floatx4*>(src + q * 4);
    }
    {
      const float* src = ot + ((size_t)(b * 8 + h)) * 4096 + srow * 64 + sc * 16;
      #pragma unroll
      for (int q = 0; q < 4; ++q)
        *reinterpret_cast<floatx4*>(&otS[srow][sc * 16 + q * 4]) =
            *reinterpret_cast<const floatx4*>(src + q * 4);
    }
    __syncthreads();
    float wcol[64];
    #pragma unroll
    for (int c = 0; c < 64; ++c) wcol[c] = woS[c][jl];
    #pragma unroll
    for (int g = 0; g < 16; ++g) {
      int gg = s4 * 16 + g;
      float a = 0.f;
      #pragma unroll
      for (int c = 0; c < 64; ++c) a += otS[gg][c] * wcol[c];
      McatT[((size_t)b * 512 + (size_t)jt * 64 + jl) * 512 + h * 64 + gg] = (bf16)a;
    }
    __syncthreads();
  }
}

// ---------------------------------------------------------------------------
extern "C" void kernel_launch(void* const* d_in, const int* in_sizes, int n_in,
                              void* d_out, int out_size, void* d_ws, size_t ws_size,
                              hipStream_t stream)
{
  const float* x      = (const float*)d_in[0];
  const float* contxt = (const float*)d_in[1];
  const float* Wx     = (const float*)d_in[2];
  const float* bx     = (const float*)d_in[3];
  const float* Wfx    = (const float*)d_in[4];
  const float* bfx    = (const float*)d_in[5];
  const float* Wslice = (const float*)d_in[6];
  const float* bslice = (const float*)d_in[7];
  const float* temp   = (const float*)d_in[8];
  const float* Wq  = (const float*)d_in[9];  const float* bq  = (const float*)d_in[10];
  const float* Wk  = (const float*)d_in[11]; const float* bk  = (const float*)d_in[12];
  const float* Wv  = (const float*)d_in[13]; const float* bv  = (const float*)d_in[14];
  const float* Wcq = (const float*)d_in[15]; const float* bcq = (const float*)d_in[16];
  const float* Wck = (const float*)d_in[17]; const float* bck = (const float*)d_in[18];
  const float* Wcv = (const float*)d_in[19]; const float* bcv = (const float*)d_in[20];
  const float* smix = (const float*)d_in[21];
  const float* Wo = (const float*)d_in[22];  const float* bo = (const float*)d_in[23];
  float* out = (float*)d_out;

  char* ws = (char*)d_ws;
  bf16*  midbuf = (bf16*)(ws + 0);             // 65536 x 1024 bf16 (fx | w)
  bf16*  xb     = (bf16*)(ws + 134217728);     // 65536 x 512 bf16
  bf16*  WcatT  = (bf16*)(ws + 201326592);     // 1024 x 512 bf16
  bf16*  McatT  = (bf16*)(ws + 202375168);     // 2 x 512 x 512 bf16
  float* bcat   = (float*)(ws + 203423744);    // 1024 f32
  float* traw   = (float*)(ws + 203427840);    // 16*4096 f32
  float* norm   = (float*)(ws + 203689984);    // 16*64 f32 (adjacent to traw)
  float* otbuf  = (float*)(ws + 203694080);    // 16*4096 f32
  float* ckbuf  = (float*)(ws + 203956224);    // 16*4096 f32
  float* cvbuf  = (float*)(ws + 204218368);    // 16*4096 f32

  // prep: convert (16384) + WcatT build (1024) + zero traw/norm (65)
  k_prep<<<dim3(17473), 256, 0, stream>>>(x, xb, Wx, bx, Wfx, bfx, Wslice, bslice,
                                          temp, WcatT, bcat, traw);

  // GEMM 1 (+softmax epilogue on logits half): xb @ WcatT^T -> midbuf
  k_gemm<bf16, true><<<dim3(4096, 1, 1), 256, 0, stream>>>(
      xb, WcatT, midbuf, bcat, 0, 0, 0, 512, 1024, 8);

  k_tokens<<<dim3(32, 16), 256, 0, stream>>>(midbuf, traw, norm);

  k_ctx<<<dim3(16, 2), 256, 0, stream>>>(contxt, Wck, bck, Wcv, bcv, ckbuf, cvbuf);

  k_attn<<<dim3(16), 256, 0, stream>>>(traw, norm, Wq, bq, Wk, bk, Wv, bv, Wcq, bcq,
                                       ckbuf, cvbuf, smix, otbuf);

  k_mcat<<<dim3(8, 2), 256, 0, stream>>>(otbuf, Wo, McatT);

  // GEMM 2: w[b] (32768x512, lda=1024) @ McatT[b]^T + bo -> out[b] (fp32)
  k_gemm<float, false><<<dim3(1024, 1, 2), 256, 0, stream>>>(
      midbuf + 512, McatT, out, bo,
      (long)32768 * 1024, (long)512 * 512, (long)32768 * 512, 1024, 512, 4);
}

// Round 4
// 642.551 us; speedup vs baseline: 1.2806x; 1.1683x over previous
//
#include <hip/hip_runtime.h>
#include <hip/hip_bf16.h>
#include <cstdint>

typedef __bf16 bf16;
typedef bf16 bf16x8 __attribute__((ext_vector_type(8)));
typedef float floatx4 __attribute__((ext_vector_type(4)));

#define EPS_F 1e-5f

__device__ __forceinline__ void async16(const bf16* g, bf16* l)
{
  __builtin_amdgcn_global_load_lds(
      (const __attribute__((address_space(1))) void*)g,
      (__attribute__((address_space(3))) void*)l, 16, 0, 0);
}

// ---------------------------------------------------------------------------
// k_prep: fused  [0,16384): x fp32->bf16
//                [16384,17408): build WcatT/bcat
//                [17408,17473): zero traw+norm (65 * 1024 floats)
//                [17473,17505): ck/cv = context(b,h) @ Wck/Wcv + bias
// ---------------------------------------------------------------------------
__global__ void k_prep(const float* __restrict__ x, bf16* __restrict__ xb,
                       const float* __restrict__ Wx, const float* __restrict__ bx,
                       const float* __restrict__ Wfx, const float* __restrict__ bfx,
                       const float* __restrict__ Wslice, const float* __restrict__ bslice,
                       const float* __restrict__ temp,
                       bf16* __restrict__ WcatT, float* __restrict__ bcat,
                       float* __restrict__ zbase,
                       const float* __restrict__ ctx,
                       const float* __restrict__ Wck, const float* __restrict__ bck,
                       const float* __restrict__ Wcv, const float* __restrict__ bcv,
                       float* __restrict__ ckbuf, float* __restrict__ cvbuf)
{
  __shared__ float sW[64];
  int bb = blockIdx.x;
  int t = threadIdx.x;
  if (bb < 16384) {
    long i = ((long)bb * 256 + t) * 8;
    floatx4 a = *reinterpret_cast<const floatx4*>(x + i);
    floatx4 b = *reinterpret_cast<const floatx4*>(x + i + 4);
    bf16x8 o;
    #pragma unroll
    for (int e = 0; e < 4; ++e) { o[e] = (bf16)a[e]; o[4 + e] = (bf16)b[e]; }
    *reinterpret_cast<bf16x8*>(xb + i) = o;
  } else if (bb < 17408) {
    int j = bb - 16384;
    if (j < 512) {
      for (int c = t; c < 512; c += 256)
        WcatT[(size_t)j * 512 + c] = (bf16)Wfx[(size_t)c * 512 + j];
      if (t == 0) bcat[j] = bfx[j];
    } else {
      int jj = j - 512;
      int h = jj >> 6, g = jj & 63;
      if (t < 64) sW[t] = Wslice[t * 64 + g];
      __syncthreads();
      float tv = temp[h];
      tv = fminf(fmaxf(tv, 0.1f), 5.0f);
      float invt = 1.0f / tv;
      for (int c = t; c < 512; c += 256) {
        const float* wrow = Wx + (size_t)c * 512 + h * 64;
        float acc = 0.f;
        #pragma unroll
        for (int d = 0; d < 64; ++d) acc += wrow[d] * sW[d];
        WcatT[(size_t)j * 512 + c] = (bf16)(acc * invt);
      }
      if (t == 0) {
        float acc = 0.f;
        for (int d = 0; d < 64; ++d) acc += bx[h * 64 + d] * sW[d];
        bcat[j] = (acc + bslice[g]) * invt;
      }
    }
  } else if (bb < 17473) {
    int z = bb - 17408;
    floatx4 zf = {0.f, 0.f, 0.f, 0.f};
    *reinterpret_cast<floatx4*>(&zbase[((long)z * 256 + t) * 4]) = zf;
  } else {
    int z = bb - 17473;  // 0..31
    int bh = z >> 1, which = z & 1;
    const float* W = which ? Wcv : Wck;
    const float* bvec = which ? bcv : bck;
    float* outp = which ? cvbuf : ckbuf;
    int r = t >> 2, c0 = (t & 3) * 16;
    const float* crow = ctx + ((size_t)bh * 64 + r) * 256;
    float acc[16] = {};
    for (int e4 = 0; e4 < 64; ++e4) {
      floatx4 cvv = *(const floatx4*)(crow + e4 * 4);
      #pragma unroll
      for (int ee = 0; ee < 4; ++ee) {
        float cval = cvv[ee];
        int e = e4 * 4 + ee;
        #pragma unroll
        for (int q = 0; q < 4; ++q) {
          floatx4 w4 = *(const floatx4*)(W + e * 64 + c0 + q * 4);
          acc[q * 4 + 0] += cval * w4[0];
          acc[q * 4 + 1] += cval * w4[1];
          acc[q * 4 + 2] += cval * w4[2];
          acc[q * 4 + 3] += cval * w4[3];
        }
      }
    }
    size_t ob = (size_t)bh * 4096 + r * 64 + c0;
    #pragma unroll
    for (int i = 0; i < 16; ++i) outp[ob + i] = acc[i] + bvec[c0 + i];
  }
}

// ---------------------------------------------------------------------------
// k_gemm: C(M x Nc) = A(M x 512, lda) @ BT(Nc x 512)^T + bias, fp32 acc.
// 128x128 tile, 4 waves 2x2. global_load_lds 16B staging, unpadded LDS.
// XCD swizzle. SM: per-head softmax epilogue for N0>=512 blocks.
// ---------------------------------------------------------------------------
template <typename OutT, bool SM>
__global__ __launch_bounds__(256, 2) void k_gemm(
    const bf16* __restrict__ A, const bf16* __restrict__ BT,
    OutT* __restrict__ C, const float* __restrict__ bias,
    long Abatch, long Bbatch, long Cbatch, int lda, int ldc, int grid_n)
{
  __shared__ bf16 As[128 * 64];
  __shared__ bf16 Bs[128 * 64];
  const int t = threadIdx.x;
  const int lane = t & 63;
  const int wave = t >> 6;
  const int wm = wave >> 1, wn = wave & 1;
  const int zb = blockIdx.z;
  const bf16* Ab = A + (long)zb * Abatch;
  const bf16* Bb = BT + (long)zb * Bbatch;
  OutT* Cb = C + (long)zb * Cbatch;

  const int L = blockIdx.x;
  const int cx = L & 7;
  const int nb = (L >> 3) % grid_n;
  const int chunk = L / (8 * grid_n);
  const int M0 = (chunk * 8 + cx) * 128;
  const int N0 = nb * 128;

  const int lm = lane & 15;
  const int quad = lane >> 4;
  const int srow = lane >> 3;
  const int sc8 = lane & 7;

  floatx4 acc[4][4] = {};

  for (int kt = 0; kt < 8; ++kt) {
    const int k0 = kt * 64;
    const bf16* gA = Ab + (long)(M0 + wave * 32 + srow) * lda + k0 + sc8 * 8;
    const bf16* gB = Bb + (long)(N0 + wave * 32 + srow) * 512 + k0 + sc8 * 8;
    bf16* lA = &As[wave * 2048];
    bf16* lB = &Bs[wave * 2048];
    #pragma unroll
    for (int i = 0; i < 4; ++i) {
      async16(gA + (long)i * 8 * lda, lA + i * 512);
      async16(gB + (long)i * 8 * 512, lB + i * 512);
    }
    __syncthreads();
    #pragma unroll
    for (int s = 0; s < 2; ++s) {
      const int kl = s * 32 + quad * 8;
      bf16x8 af[4], bfr[4];
      #pragma unroll
      for (int i = 0; i < 4; ++i)
        af[i] = *reinterpret_cast<const bf16x8*>(&As[(wm * 64 + i * 16 + lm) * 64 + kl]);
      #pragma unroll
      for (int j = 0; j < 4; ++j)
        bfr[j] = *reinterpret_cast<const bf16x8*>(&Bs[(wn * 64 + j * 16 + lm) * 64 + kl]);
      #pragma unroll
      for (int i = 0; i < 4; ++i)
        #pragma unroll
        for (int j = 0; j < 4; ++j)
          acc[i][j] = __builtin_amdgcn_mfma_f32_16x16x32_bf16(af[i], bfr[j], acc[i][j], 0, 0, 0);
    }
    __syncthreads();
  }

  float bv[4];
  #pragma unroll
  for (int j = 0; j < 4; ++j) bv[j] = bias[N0 + wn * 64 + j * 16 + lm];

  if (SM && N0 >= 512) {
    #pragma unroll
    for (int i = 0; i < 4; ++i) {
      #pragma unroll
      for (int r = 0; r < 4; ++r) {
        float v[4];
        #pragma unroll
        for (int j = 0; j < 4; ++j) v[j] = acc[i][j][r] + bv[j];
        float m = fmaxf(fmaxf(v[0], v[1]), fmaxf(v[2], v[3]));
        m = fmaxf(m, __shfl_xor(m, 1));
        m = fmaxf(m, __shfl_xor(m, 2));
        m = fmaxf(m, __shfl_xor(m, 4));
        m = fmaxf(m, __shfl_xor(m, 8));
        float e[4], s = 0.f;
        #pragma unroll
        for (int j = 0; j < 4; ++j) { e[j] = __expf(v[j] - m); s += e[j]; }
        s += __shfl_xor(s, 1);
        s += __shfl_xor(s, 2);
        s += __shfl_xor(s, 4);
        s += __shfl_xor(s, 8);
        float inv = 1.0f / s;
        const long gr = M0 + wm * 64 + i * 16 + quad * 4 + r;
        #pragma unroll
        for (int j = 0; j < 4; ++j)
          Cb[gr * ldc + N0 + wn * 64 + j * 16 + lm] = (OutT)(e[j] * inv);
      }
    }
  } else {
    #pragma unroll
    for (int i = 0; i < 4; ++i) {
      const int gr0 = M0 + wm * 64 + i * 16 + quad * 4;
      #pragma unroll
      for (int j = 0; j < 4; ++j) {
        const int gc = N0 + wn * 64 + j * 16 + lm;
        #pragma unroll
        for (int r = 0; r < 4; ++r)
          Cb[(long)(gr0 + r) * ldc + gc] = (OutT)(acc[i][j][r] + bv[j]);
      }
    }
  }
}

// ---------------------------------------------------------------------------
// k_tokens: per (b,h): raw[g,c] += sum_n w[n,g]*fx[n,c]; norm[g] += sum_n w
// ---------------------------------------------------------------------------
__global__ __launch_bounds__(256) void k_tokens(const bf16* __restrict__ mid,
                                                float* __restrict__ raw,
                                                float* __restrict__ norm)
{
  __shared__ float wt[64][72];
  __shared__ float ft[64][72];
  int kc = blockIdx.x;
  int bh = blockIdx.y;
  int b = bh >> 3, h = bh & 7;
  long rbase = (long)b * 32768 + (long)kc * 1024;
  int t = threadIdx.x;
  int lrow = t >> 2, seg = t & 3;
  int tg = t >> 4, tc = t & 15;
  float acc[4][4] = {};
  float na[4] = {0.f, 0.f, 0.f, 0.f};
  for (int sub = 0; sub < 16; ++sub) {
    long r0 = rbase + sub * 64 + lrow;
    const bf16* fsrc = mid + r0 * 1024 + h * 64 + seg * 16;
    const bf16* wsrc = mid + r0 * 1024 + 512 + h * 64 + seg * 16;
    bf16x8 w0 = *(const bf16x8*)wsrc, w1 = *(const bf16x8*)(wsrc + 8);
    bf16x8 f0 = *(const bf16x8*)fsrc, f1 = *(const bf16x8*)(fsrc + 8);
    #pragma unroll
    for (int e = 0; e < 8; ++e) {
      wt[lrow][seg * 16 + e] = (float)w0[e];
      wt[lrow][seg * 16 + 8 + e] = (float)w1[e];
      ft[lrow][seg * 16 + e] = (float)f0[e];
      ft[lrow][seg * 16 + 8 + e] = (float)f1[e];
    }
    __syncthreads();
    #pragma unroll 4
    for (int n = 0; n < 64; ++n) {
      floatx4 wv = *(const floatx4*)&wt[n][tg * 4];
      floatx4 fv = *(const floatx4*)&ft[n][tc * 4];
      #pragma unroll
      for (int gi = 0; gi < 4; ++gi)
        #pragma unroll
        for (int ci = 0; ci < 4; ++ci) acc[gi][ci] += wv[gi] * fv[ci];
      if (tc == 0) {
        #pragma unroll
        for (int gi = 0; gi < 4; ++gi) na[gi] += wv[gi];
      }
    }
    __syncthreads();
  }
  float* rb = raw + (size_t)bh * 4096;
  #pragma unroll
  for (int gi = 0; gi < 4; ++gi)
    #pragma unroll
    for (int ci = 0; ci < 4; ++ci)
      atomicAdd(&rb[(tg * 4 + gi) * 64 + tc * 4 + ci], acc[gi][ci]);
  if (tc == 0) {
    #pragma unroll
    for (int gi = 0; gi < 4; ++gi) atomicAdd(&norm[bh * 64 + tg * 4 + gi], na[gi]);
  }
}

// ---------------------------------------------------------------------------
// k_attn2: grid (16 bh, 2 path). path 0: self-attn -> sabuf.
//          path 1: cross-attn (cq proj; ck/cv precomputed) -> cabuf.
// Gate mix happens later in k_mcat.
// ---------------------------------------------------------------------------
__global__ __launch_bounds__(256) void k_attn2(
    const float* __restrict__ raw, const float* __restrict__ norm,
    const float* __restrict__ Wq, const float* __restrict__ bq,
    const float* __restrict__ Wk, const float* __restrict__ bk,
    const float* __restrict__ Wv, const float* __restrict__ bv,
    const float* __restrict__ Wcq, const float* __restrict__ bcq,
    const float* __restrict__ ck, const float* __restrict__ cv,
    float* __restrict__ sabuf, float* __restrict__ cabuf)
{
  __shared__ float T0[4096];  // tokens -> P
  __shared__ float T1[4096];  // q  | ck
  __shared__ float T2[4096];  // k  | cv
  __shared__ float T3[4096];  // v  | cq
  int bh = blockIdx.x;
  int path = blockIdx.y;
  int t = threadIdx.x;
  int r = t >> 2;
  int c0 = (t & 3) * 16;
  size_t base = (size_t)bh * 4096;

  // tokens (both paths); path 1 also stages ck/cv (independent)
  float invn = 1.0f / (norm[bh * 64 + r] + EPS_F);
  #pragma unroll
  for (int i = 0; i < 16; ++i)
    T0[r * 64 + c0 + i] = raw[base + r * 64 + c0 + i] * invn;
  if (path == 1) {
    #pragma unroll
    for (int i = 0; i < 16; ++i) {
      T1[r * 64 + c0 + i] = ck[base + r * 64 + c0 + i];
      T2[r * 64 + c0 + i] = cv[base + r * 64 + c0 + i];
    }
  }
  __syncthreads();

  if (path == 0) {
    float aq[16] = {}, ak[16] = {}, av[16] = {};
    for (int d = 0; d < 64; ++d) {
      float x = T0[r * 64 + d];
      #pragma unroll
      for (int q = 0; q < 4; ++q) {
        floatx4 wq = *(const floatx4*)(Wq + d * 64 + c0 + q * 4);
        floatx4 wk = *(const floatx4*)(Wk + d * 64 + c0 + q * 4);
        floatx4 wv = *(const floatx4*)(Wv + d * 64 + c0 + q * 4);
        #pragma unroll
        for (int e = 0; e < 4; ++e) {
          aq[q * 4 + e] += x * wq[e];
          ak[q * 4 + e] += x * wk[e];
          av[q * 4 + e] += x * wv[e];
        }
      }
    }
    #pragma unroll
    for (int i = 0; i < 16; ++i) {
      T1[r * 64 + c0 + i] = aq[i] + bq[c0 + i];
      T2[r * 64 + c0 + i] = ak[i] + bk[c0 + i];
      T3[r * 64 + c0 + i] = av[i] + bv[c0 + i];
    }
  } else {
    float acq[16] = {};
    for (int d = 0; d < 64; ++d) {
      float x = T0[r * 64 + d];
      #pragma unroll
      for (int q = 0; q < 4; ++q) {
        floatx4 wc = *(const floatx4*)(Wcq + d * 64 + c0 + q * 4);
        #pragma unroll
        for (int e = 0; e < 4; ++e) acq[q * 4 + e] += x * wc[e];
      }
    }
    #pragma unroll
    for (int i = 0; i < 16; ++i) T3[r * 64 + c0 + i] = acq[i] + bcq[c0 + i];
  }
  __syncthreads();

  // scores q(T1|T3) vs k(T2|T1), softmax -> T0
  {
    const float* Q = (path == 0) ? T1 : T3;
    const float* K = (path == 0) ? T2 : T1;
    float p[16];
    float mx = -1e30f;
    #pragma unroll
    for (int i = 0; i < 16; ++i) {
      int cc = c0 + i;
      float s = 0.f;
      #pragma unroll
      for (int d4 = 0; d4 < 16; ++d4) {
        floatx4 qv = *(const floatx4*)&Q[r * 64 + d4 * 4];
        floatx4 kv = *(const floatx4*)&K[cc * 64 + d4 * 4];
        s += qv[0] * kv[0] + qv[1] * kv[1] + qv[2] * kv[2] + qv[3] * kv[3];
      }
      p[i] = s * 0.125f;
      mx = fmaxf(mx, p[i]);
    }
    mx = fmaxf(mx, __shfl_xor(mx, 1));
    mx = fmaxf(mx, __shfl_xor(mx, 2));
    float sum = 0.f;
    #pragma unroll
    for (int i = 0; i < 16; ++i) { p[i] = __expf(p[i] - mx); sum += p[i]; }
    sum += __shfl_xor(sum, 1);
    sum += __shfl_xor(sum, 2);
    float inv = 1.0f / sum;
    #pragma unroll
    for (int i = 0; i < 16; ++i) T0[r * 64 + c0 + i] = p[i] * inv;
  }
  __syncthreads();

  // out = P @ v(T3|T2)
  {
    const float* V = (path == 0) ? T3 : T2;
    float* dst = (path == 0) ? sabuf : cabuf;
    float oa[16] = {};
    for (int g = 0; g < 64; ++g) {
      float pv = T0[r * 64 + g];
      #pragma unroll
      for (int i4 = 0; i4 < 4; ++i4) {
        floatx4 vv = *(const floatx4*)&V[g * 64 + c0 + i4 * 4];
        oa[i4 * 4 + 0] += pv * vv[0];
        oa[i4 * 4 + 1] += pv * vv[1];
        oa[i4 * 4 + 2] += pv * vv[2];
        oa[i4 * 4 + 3] += pv * vv[3];
      }
    }
    #pragma unroll
    for (int i = 0; i < 16; ++i) dst[base + r * 64 + c0 + i] = oa[i];
  }
}

// ---------------------------------------------------------------------------
// k_mcat2: grid (8 jt, 16 bh). ot = g*sa+(1-g)*ca mixed during staging.
// McatT[b][jt*64+j][h*64+g] = sum_c ot[g][c] * Wo[h*64+c][jt*64+j]
// woT transposed in LDS (pad 68: 2-way free); all-float4 inner loop.
// ---------------------------------------------------------------------------
__global__ __launch_bounds__(256) void k_mcat2(const float* __restrict__ sabuf,
                                               const float* __restrict__ cabuf,
                                               const float* __restrict__ smix,
                                               const float* __restrict__ Wo,
                                               bf16* __restrict__ McatT)
{
  __shared__ float woT[64][68];
  __shared__ float otS[64][68];
  int jt = blockIdx.x;
  int bh = blockIdx.y;
  int b = bh >> 3, h = bh & 7;
  int t = threadIdx.x;
  float gm = 1.0f / (1.0f + __expf(-smix[0]));
  int c = t >> 2, sc = t & 3;

  // stage Wo^T (transpose via regs)
  {
    const float* src = Wo + (size_t)(h * 64 + c) * 512 + jt * 64 + sc * 16;
    float tmp[16];
    #pragma unroll
    for (int q = 0; q < 4; ++q) {
      floatx4 v = *(const floatx4*)(src + q * 4);
      tmp[q * 4 + 0] = v[0]; tmp[q * 4 + 1] = v[1];
      tmp[q * 4 + 2] = v[2]; tmp[q * 4 + 3] = v[3];
    }
    #pragma unroll
    for (int ji = 0; ji < 16; ++ji) woT[sc * 16 + ji][c] = tmp[ji];
  }
  // stage ot = mix(sa, ca)
  {
    const float* sp = sabuf + (size_t)bh * 4096 + c * 64 + sc * 16;
    const float* cp = cabuf + (size_t)bh * 4096 + c * 64 + sc * 16;
    #pragma unroll
    for (int q = 0; q < 4; ++q) {
      floatx4 s4 = *(const floatx4*)(sp + q * 4);
      floatx4 c4 = *(const floatx4*)(cp + q * 4);
      floatx4 m4;
      #pragma unroll
      for (int e = 0; e < 4; ++e) m4[e] = gm * s4[e] + (1.0f - gm) * c4[e];
      *(floatx4*)&otS[c][sc * 16 + q * 4] = m4;
    }
  }
  __syncthreads();

  int j = t >> 2, g0 = (t & 3) * 16;
  float acc[16] = {};
  for (int c4 = 0; c4 < 16; ++c4) {
    floatx4 wv = *(const floatx4*)&woT[j][c4 * 4];
    #pragma unroll
    for (int gi = 0; gi < 16; ++gi) {
      floatx4 ov = *(const floatx4*)&otS[g0 + gi][c4 * 4];
      acc[gi] += wv[0] * ov[0] + wv[1] * ov[1] + wv[2] * ov[2] + wv[3] * ov[3];
    }
  }
  size_t row = (size_t)b * 512 + jt * 64 + j;
  bf16x8 o0, o1;
  #pragma unroll
  for (int e = 0; e < 8; ++e) { o0[e] = (bf16)acc[e]; o1[e] = (bf16)acc[8 + e]; }
  *reinterpret_cast<bf16x8*>(&McatT[row * 512 + h * 64 + g0]) = o0;
  *reinterpret_cast<bf16x8*>(&McatT[row * 512 + h * 64 + g0 + 8]) = o1;
}

// ---------------------------------------------------------------------------
extern "C" void kernel_launch(void* const* d_in, const int* in_sizes, int n_in,
                              void* d_out, int out_size, void* d_ws, size_t ws_size,
                              hipStream_t stream)
{
  const float* x      = (const float*)d_in[0];
  const float* contxt = (const float*)d_in[1];
  const float* Wx     = (const float*)d_in[2];
  const float* bx     = (const float*)d_in[3];
  const float* Wfx    = (const float*)d_in[4];
  const float* bfx    = (const float*)d_in[5];
  const float* Wslice = (const float*)d_in[6];
  const float* bslice = (const float*)d_in[7];
  const float* temp   = (const float*)d_in[8];
  const float* Wq  = (const float*)d_in[9];  const float* bq  = (const float*)d_in[10];
  const float* Wk  = (const float*)d_in[11]; const float* bk  = (const float*)d_in[12];
  const float* Wv  = (const float*)d_in[13]; const float* bv  = (const float*)d_in[14];
  const float* Wcq = (const float*)d_in[15]; const float* bcq = (const float*)d_in[16];
  const float* Wck = (const float*)d_in[17]; const float* bck = (const float*)d_in[18];
  const float* Wcv = (const float*)d_in[19]; const float* bcv = (const float*)d_in[20];
  const float* smix = (const float*)d_in[21];
  const float* Wo = (const float*)d_in[22];  const float* bo = (const float*)d_in[23];
  float* out = (float*)d_out;

  char* ws = (char*)d_ws;
  bf16*  midbuf = (bf16*)(ws + 0);             // 65536 x 1024 bf16 (fx | w)
  bf16*  xb     = (bf16*)(ws + 134217728);     // 65536 x 512 bf16
  bf16*  WcatT  = (bf16*)(ws + 201326592);     // 1024 x 512 bf16
  bf16*  McatT  = (bf16*)(ws + 202375168);     // 2 x 512 x 512 bf16
  float* bcat   = (float*)(ws + 203423744);    // 1024 f32
  float* traw   = (float*)(ws + 203427840);    // 16*4096 f32
  float* norm   = (float*)(ws + 203689984);    // 16*64 f32 (adjacent to traw)
  float* sabuf  = (float*)(ws + 203694080);    // 16*4096 f32
  float* cabuf  = (float*)(ws + 203956224);    // 16*4096 f32
  float* ckbuf  = (float*)(ws + 204218368);    // 16*4096 f32
  float* cvbuf  = (float*)(ws + 204480512);    // 16*4096 f32  (end ~204.75 MB)

  // prep: convert (16384) + WcatT (1024) + zero traw/norm (65) + ck/cv (32)
  k_prep<<<dim3(17505), 256, 0, stream>>>(x, xb, Wx, bx, Wfx, bfx, Wslice, bslice,
                                          temp, WcatT, bcat, traw,
                                          contxt, Wck, bck, Wcv, bcv, ckbuf, cvbuf);

  // GEMM 1 (+softmax epilogue): xb @ WcatT^T -> midbuf
  k_gemm<bf16, true><<<dim3(4096, 1, 1), 256, 0, stream>>>(
      xb, WcatT, midbuf, bcat, 0, 0, 0, 512, 1024, 8);

  k_tokens<<<dim3(32, 16), 256, 0, stream>>>(midbuf, traw, norm);

  k_attn2<<<dim3(16, 2), 256, 0, stream>>>(traw, norm, Wq, bq, Wk, bk, Wv, bv,
                                           Wcq, bcq, ckbuf, cvbuf, sabuf, cabuf);

  k_mcat2<<<dim3(8, 16), 256, 0, stream>>>(sabuf, cabuf, smix, Wo, McatT);

  // GEMM 2: w[b] (32768x512, lda=1024) @ McatT[b]^T + bo -> out[b] (fp32)
  k_gemm<float, false><<<dim3(1024, 1, 2), 256, 0, stream>>>(
      midbuf + 512, McatT, out, bo,
      (long)32768 * 1024, (long)512 * 512, (long)32768 * 512, 1024, 512, 4);
}